// Round 1
// baseline (240.385 us; speedup 1.0000x reference)
//
#include <hip/hip_runtime.h>
#include <hip/hip_bf16.h>
#include <stdint.h>

// ---------------------------------------------------------------------------
// Self-attention (B=4, S=2048, D=H=1024), fp32 in/out, bf16 MFMA compute.
// Stages: cast/transpose -> QKV GEMM -> S=QK^T/32 GEMM -> softmax -> V^T ->
//         O=PV GEMM. All GEMMs share one 128x128-tile mfma_16x16x32_bf16 kernel.
// ---------------------------------------------------------------------------

typedef __attribute__((ext_vector_type(8))) short bf16x8;  // 8 bf16 = 4 VGPR
typedef __attribute__((ext_vector_type(4))) float f32x4;

#define BATCH 4
#define SEQ   2048
#define DIM   1024
#define MROWS (BATCH * SEQ)          // 8192
#define NQKV  (3 * DIM)              // 3072

__device__ __forceinline__ unsigned short f2bf(float f) {
    union { float f; uint32_t u; } v; v.f = f;
    uint32_t u = v.u;
    return (unsigned short)((u + 0x7FFFu + ((u >> 16) & 1u)) >> 16);  // RNE
}
__device__ __forceinline__ float bf2f(unsigned short b) {
    union { uint32_t u; float f; } v; v.u = ((uint32_t)b) << 16;
    return v.f;
}

// ---- stage 1a: cast x (fp32) -> bf16, 8 elems/thread -----------------------
__global__ void cast_x_kernel(const float* __restrict__ x,
                              unsigned short* __restrict__ xb, int n8) {
    int i = blockIdx.x * blockDim.x + threadIdx.x;
    if (i >= n8) return;
    const float4* p = reinterpret_cast<const float4*>(x) + (size_t)i * 2;
    float4 a = p[0], b = p[1];
    union { unsigned short u[8]; uint4 v; } o;
    o.u[0] = f2bf(a.x); o.u[1] = f2bf(a.y); o.u[2] = f2bf(a.z); o.u[3] = f2bf(a.w);
    o.u[4] = f2bf(b.x); o.u[5] = f2bf(b.y); o.u[6] = f2bf(b.z); o.u[7] = f2bf(b.w);
    reinterpret_cast<uint4*>(xb)[i] = o.v;
}

// ---- stage 1b: W [D][H] fp32 -> Wt_cat [3*H][D] bf16 (transpose + cast) ----
__global__ void transpose_w_kernel(const float* __restrict__ Wq,
                                   const float* __restrict__ Wk,
                                   const float* __restrict__ Wv,
                                   unsigned short* __restrict__ Wt) {
    __shared__ float tile[32][33];
    const float* W = (blockIdx.z == 0) ? Wq : (blockIdx.z == 1 ? Wk : Wv);
    int d0 = blockIdx.x * 32, h0 = blockIdx.y * 32;
    int t = threadIdx.x;
    int lr = t >> 5, lc = t & 31;
    #pragma unroll
    for (int r = 0; r < 4; ++r) {
        int row = r * 8 + lr;
        tile[row][lc] = W[(size_t)(d0 + row) * DIM + h0 + lc];
    }
    __syncthreads();
    unsigned short* out = Wt + (size_t)blockIdx.z * DIM * DIM;
    #pragma unroll
    for (int r = 0; r < 4; ++r) {
        int hrow = r * 8 + lr;
        out[(size_t)(h0 + hrow) * DIM + d0 + lc] = f2bf(tile[lc][hrow]);
    }
}

// ---- stage 1c: bias concat -------------------------------------------------
__global__ void concat_bias_kernel(const float* __restrict__ bq,
                                   const float* __restrict__ bk,
                                   const float* __restrict__ bv,
                                   float* __restrict__ out) {
    int i = blockIdx.x * blockDim.x + threadIdx.x;
    if (i >= NQKV) return;
    out[i] = (i < DIM) ? bq[i] : (i < 2 * DIM ? bk[i - DIM] : bv[i - 2 * DIM]);
}

// ---- generic bf16 MFMA GEMM: C[m][n] = scale * sum_k A[m][k]*B[n][k] + bias[n]
// A row-major [M][K] (lda), B stored [N][K] (ldb), 128x128 tile, BK=32,
// 4 waves of 64x64, mfma_f32_16x16x32_bf16.
template <bool OUT_BF16, bool HAS_BIAS>
__global__ __launch_bounds__(256) void gemm_kernel(
    const unsigned short* __restrict__ A, int lda, size_t strideA,
    const unsigned short* __restrict__ B, int ldb, size_t strideB,
    void* __restrict__ Cv, int ldc, size_t strideC,
    const float* __restrict__ bias, float scale, int K)
{
    __shared__ unsigned short a_lds[128][40];  // +8 pad: 80B row stride, 2-way banks = free
    __shared__ unsigned short b_lds[128][40];

    A += (size_t)blockIdx.z * strideA;
    B += (size_t)blockIdx.z * strideB;

    const int m0 = blockIdx.y * 128;
    const int n0 = blockIdx.x * 128;

    const int t    = threadIdx.x;
    const int lane = t & 63;
    const int wid  = t >> 6;
    const int wm   = (wid >> 1) * 64;
    const int wn   = (wid & 1) * 64;
    const int fr   = lane & 15;   // A-row / B-col within fragment
    const int kg   = lane >> 4;   // k-group (8 elems each)

    // staging: 512 chunks of 8 bf16; thread covers chunk t and t+256
    const int r0 = t >> 2,        o0 = (t & 3) * 8;
    const int r1 = (t + 256) >> 2, o1 = ((t + 256) & 3) * 8;

    const unsigned short* Ar0 = A + (size_t)(m0 + r0) * lda + o0;
    const unsigned short* Ar1 = A + (size_t)(m0 + r1) * lda + o1;
    const unsigned short* Br0 = B + (size_t)(n0 + r0) * ldb + o0;
    const unsigned short* Br1 = B + (size_t)(n0 + r1) * ldb + o1;

    f32x4 acc[4][4] = {};

    for (int k0 = 0; k0 < K; k0 += 32) {
        uint4 av0 = *reinterpret_cast<const uint4*>(Ar0 + k0);
        uint4 av1 = *reinterpret_cast<const uint4*>(Ar1 + k0);
        uint4 bv0 = *reinterpret_cast<const uint4*>(Br0 + k0);
        uint4 bv1 = *reinterpret_cast<const uint4*>(Br1 + k0);
        *reinterpret_cast<uint4*>(&a_lds[r0][o0]) = av0;
        *reinterpret_cast<uint4*>(&a_lds[r1][o1]) = av1;
        *reinterpret_cast<uint4*>(&b_lds[r0][o0]) = bv0;
        *reinterpret_cast<uint4*>(&b_lds[r1][o1]) = bv1;
        __syncthreads();

        bf16x8 af[4], bfr[4];
        #pragma unroll
        for (int m = 0; m < 4; ++m)
            af[m] = *reinterpret_cast<const bf16x8*>(&a_lds[wm + m * 16 + fr][kg * 8]);
        #pragma unroll
        for (int n = 0; n < 4; ++n)
            bfr[n] = *reinterpret_cast<const bf16x8*>(&b_lds[wn + n * 16 + fr][kg * 8]);

        #pragma unroll
        for (int m = 0; m < 4; ++m)
            #pragma unroll
            for (int n = 0; n < 4; ++n)
                acc[m][n] = __builtin_amdgcn_mfma_f32_16x16x32_bf16(
                    af[m], bfr[n], acc[m][n], 0, 0, 0);
        __syncthreads();
    }

    // epilogue: C/D layout col = lane&15, row = (lane>>4)*4 + r  [m89-verified]
    const int rbase = wm + (lane >> 4) * 4;
    const int cbase = wn + (lane & 15);
    const size_t zoff = (size_t)blockIdx.z * strideC;
    #pragma unroll
    for (int n = 0; n < 4; ++n) {
        const int col = n0 + cbase + n * 16;
        const float bsv = HAS_BIAS ? bias[col] : 0.0f;
        #pragma unroll
        for (int m = 0; m < 4; ++m) {
            #pragma unroll
            for (int r = 0; r < 4; ++r) {
                const int rowg = m0 + rbase + m * 16 + r;
                const float v = acc[m][n][r] * scale + bsv;
                if (OUT_BF16)
                    reinterpret_cast<unsigned short*>(Cv)[zoff + (size_t)rowg * ldc + col] = f2bf(v);
                else
                    reinterpret_cast<float*>(Cv)[zoff + (size_t)rowg * ldc + col] = v;
            }
        }
    }
}

// ---- stage 4: in-place row softmax on S (bf16), one block per row ----------
__global__ __launch_bounds__(256) void softmax_kernel(unsigned short* __restrict__ S) {
    __shared__ float red[8];
    unsigned short* p = S + (size_t)blockIdx.x * SEQ;
    const int t = threadIdx.x;  // 256 threads * 8 elems = 2048
    union { uint4 v; unsigned short u[8]; } in;
    in.v = reinterpret_cast<const uint4*>(p)[t];
    float f[8];
    float m = -1e30f;
    #pragma unroll
    for (int i = 0; i < 8; ++i) { f[i] = bf2f(in.u[i]); m = fmaxf(m, f[i]); }
    #pragma unroll
    for (int off = 32; off > 0; off >>= 1) m = fmaxf(m, __shfl_xor(m, off));
    if ((t & 63) == 0) red[t >> 6] = m;
    __syncthreads();
    m = fmaxf(fmaxf(red[0], red[1]), fmaxf(red[2], red[3]));
    float s = 0.0f;
    #pragma unroll
    for (int i = 0; i < 8; ++i) { f[i] = __expf(f[i] - m); s += f[i]; }
    #pragma unroll
    for (int off = 32; off > 0; off >>= 1) s += __shfl_xor(s, off);
    __syncthreads();
    if ((t & 63) == 0) red[4 + (t >> 6)] = s;
    __syncthreads();
    s = (red[4] + red[5]) + (red[6] + red[7]);
    const float inv = 1.0f / s;
    union { uint4 v; unsigned short u[8]; } o;
    #pragma unroll
    for (int i = 0; i < 8; ++i) o.u[i] = f2bf(f[i] * inv);
    reinterpret_cast<uint4*>(p)[t] = o.v;
}

// ---- stage 5a: V [s][h] (inside QKV, stride 3072) -> Vt [h][s] per batch ---
__global__ void transpose_v_kernel(const unsigned short* __restrict__ QKV,
                                   unsigned short* __restrict__ Vt) {
    __shared__ unsigned short tile[32][34];  // 17-dw row stride: conflict-free
    const int b = blockIdx.z;
    const int s0 = blockIdx.x * 32, h0 = blockIdx.y * 32;
    const int t = threadIdx.x, lr = t >> 5, lc = t & 31;
    const unsigned short* in = QKV + (size_t)b * SEQ * NQKV + 2 * DIM;
    #pragma unroll
    for (int r = 0; r < 4; ++r) {
        int si = r * 8 + lr;
        tile[si][lc] = in[(size_t)(s0 + si) * NQKV + h0 + lc];
    }
    __syncthreads();
    unsigned short* out = Vt + (size_t)b * DIM * SEQ;
    #pragma unroll
    for (int r = 0; r < 4; ++r) {
        int hi = r * 8 + lr;
        out[(size_t)(h0 + hi) * SEQ + s0 + lc] = tile[lc][hi];
    }
}

// ---------------------------------------------------------------------------
extern "C" void kernel_launch(void* const* d_in, const int* in_sizes, int n_in,
                              void* d_out, int out_size, void* d_ws, size_t ws_size,
                              hipStream_t stream) {
    const float* x  = (const float*)d_in[0];
    const float* Wq = (const float*)d_in[1];
    const float* bq = (const float*)d_in[2];
    const float* Wk = (const float*)d_in[3];
    const float* bk = (const float*)d_in[4];
    const float* Wv = (const float*)d_in[5];
    const float* bv = (const float*)d_in[6];
    float* out = (float*)d_out;
    char* ws = (char*)d_ws;

    // workspace layout (bytes); Vt aliases xb (xb dead after QKV GEMM)
    const size_t OFF_XB   = 0;                         // 8192*1024*2  = 16,777,216
    const size_t OFF_WT   = 16777216;                  // 3072*1024*2  =  6,291,456
    const size_t OFF_BIAS = 23068672;                  // 3072*4       =     12,288
    const size_t OFF_QKV  = 23080960;                  // 8192*3072*2  = 50,331,648
    const size_t OFF_S    = 73412608;                  // 4*2048*2048*2= 33,554,432
    // total ~102 MB (Vt reuses OFF_XB)

    unsigned short* xb   = (unsigned short*)(ws + OFF_XB);
    unsigned short* Wt   = (unsigned short*)(ws + OFF_WT);
    float*          bcat = (float*)(ws + OFF_BIAS);
    unsigned short* qkv  = (unsigned short*)(ws + OFF_QKV);
    unsigned short* Smat = (unsigned short*)(ws + OFF_S);
    unsigned short* Vt   = (unsigned short*)(ws + OFF_XB);  // alias

    // 1. casts / transposes
    cast_x_kernel<<<(MROWS * DIM / 8 + 255) / 256, 256, 0, stream>>>(x, xb, MROWS * DIM / 8);
    transpose_w_kernel<<<dim3(32, 32, 3), 256, 0, stream>>>(Wq, Wk, Wv, Wt);
    concat_bias_kernel<<<12, 256, 0, stream>>>(bq, bk, bv, bcat);

    // 2. QKV = x @ W^T + b : M=8192, N=3072, K=1024, bf16 out, ldc=3072
    gemm_kernel<true, true><<<dim3(NQKV / 128, MROWS / 128, 1), 256, 0, stream>>>(
        xb, DIM, 0, Wt, DIM, 0, qkv, NQKV, 0, bcat, 1.0f, DIM);

    // 3. S = Q @ K^T / 32 : per-batch, M=N=2048, K=1024, bf16 out
    gemm_kernel<true, false><<<dim3(SEQ / 128, SEQ / 128, BATCH), 256, 0, stream>>>(
        qkv, NQKV, (size_t)SEQ * NQKV,            // Q rows
        qkv + DIM, NQKV, (size_t)SEQ * NQKV,      // K rows ([N][K] layout already)
        Smat, SEQ, (size_t)SEQ * SEQ,
        nullptr, 1.0f / 32.0f, DIM);

    // 4. softmax rows in place
    softmax_kernel<<<BATCH * SEQ, 256, 0, stream>>>(Smat);

    // 5. V^T then O = P @ V : per-batch M=2048, N=1024, K=2048, fp32 out
    transpose_v_kernel<<<dim3(SEQ / 32, DIM / 32, BATCH), 256, 0, stream>>>(qkv, Vt);
    gemm_kernel<false, false><<<dim3(DIM / 128, SEQ / 128, BATCH), 256, 0, stream>>>(
        Smat, SEQ, (size_t)SEQ * SEQ,
        Vt, SEQ, (size_t)DIM * SEQ,
        out, DIM, (size_t)SEQ * DIM,
        nullptr, 1.0f, SEQ);
}

// Round 2
// 225.431 us; speedup vs baseline: 1.0663x; 1.0663x over previous
//
#include <hip/hip_runtime.h>
#include <hip/hip_bf16.h>
#include <stdint.h>

// ---------------------------------------------------------------------------
// Self-attention (B=4, S=2048, D=H=1024), fp32 in/out, bf16 MFMA compute.
// Stages: cast/transpose -> QKV GEMM -> S=QK^T/32 GEMM -> softmax -> V^T ->
//         O=PV GEMM. GEMM uses the m97 structure: 128x128 tile, BK=32,
//         global_load_lds width=16 into linear LDS, 4 waves x 64x64.
// ---------------------------------------------------------------------------

typedef __attribute__((ext_vector_type(8))) short bf16x8;  // 8 bf16 = 4 VGPR
typedef __attribute__((ext_vector_type(4))) float f32x4;

#define BATCH 4
#define SEQ   2048
#define DIM   1024
#define MROWS (BATCH * SEQ)          // 8192
#define NQKV  (3 * DIM)              // 3072

__device__ __forceinline__ unsigned short f2bf(float f) {
    union { float f; uint32_t u; } v; v.f = f;
    uint32_t u = v.u;
    return (unsigned short)((u + 0x7FFFu + ((u >> 16) & 1u)) >> 16);  // RNE
}
__device__ __forceinline__ float bf2f(unsigned short b) {
    union { uint32_t u; float f; } v; v.u = ((uint32_t)b) << 16;
    return v.f;
}

// async global->LDS DMA, 16B per lane. LDS dest must be wave-uniform;
// HW writes base + lane*16 (m104). Global src is per-lane (m173).
__device__ __forceinline__ void gload16(const unsigned short* g, unsigned short* l) {
    __builtin_amdgcn_global_load_lds(
        (const __attribute__((address_space(1))) unsigned int*)g,
        (__attribute__((address_space(3))) unsigned int*)l,
        16, 0, 0);
}

// ---- stage 1a: cast x (fp32) -> bf16, 8 elems/thread -----------------------
__global__ void cast_x_kernel(const float* __restrict__ x,
                              unsigned short* __restrict__ xb, int n8) {
    int i = blockIdx.x * blockDim.x + threadIdx.x;
    if (i >= n8) return;
    const float4* p = reinterpret_cast<const float4*>(x) + (size_t)i * 2;
    float4 a = p[0], b = p[1];
    union { unsigned short u[8]; uint4 v; } o;
    o.u[0] = f2bf(a.x); o.u[1] = f2bf(a.y); o.u[2] = f2bf(a.z); o.u[3] = f2bf(a.w);
    o.u[4] = f2bf(b.x); o.u[5] = f2bf(b.y); o.u[6] = f2bf(b.z); o.u[7] = f2bf(b.w);
    reinterpret_cast<uint4*>(xb)[i] = o.v;
}

// ---- stage 1b: W [D][H] fp32 -> Wt_cat [3*H][D] bf16 (transpose + cast) ----
__global__ void transpose_w_kernel(const float* __restrict__ Wq,
                                   const float* __restrict__ Wk,
                                   const float* __restrict__ Wv,
                                   unsigned short* __restrict__ Wt) {
    __shared__ float tile[32][33];
    const float* W = (blockIdx.z == 0) ? Wq : (blockIdx.z == 1 ? Wk : Wv);
    int d0 = blockIdx.x * 32, h0 = blockIdx.y * 32;
    int t = threadIdx.x;
    int lr = t >> 5, lc = t & 31;
    #pragma unroll
    for (int r = 0; r < 4; ++r) {
        int row = r * 8 + lr;
        tile[row][lc] = W[(size_t)(d0 + row) * DIM + h0 + lc];
    }
    __syncthreads();
    unsigned short* out = Wt + (size_t)blockIdx.z * DIM * DIM;
    #pragma unroll
    for (int r = 0; r < 4; ++r) {
        int hrow = r * 8 + lr;
        out[(size_t)(h0 + hrow) * DIM + d0 + lc] = f2bf(tile[lc][hrow]);
    }
}

// ---- stage 1c: bias concat -------------------------------------------------
__global__ void concat_bias_kernel(const float* __restrict__ bq,
                                   const float* __restrict__ bk,
                                   const float* __restrict__ bv,
                                   float* __restrict__ out) {
    int i = blockIdx.x * blockDim.x + threadIdx.x;
    if (i >= NQKV) return;
    out[i] = (i < DIM) ? bq[i] : (i < 2 * DIM ? bk[i - DIM] : bv[i - 2 * DIM]);
}

// ---- m97-structure bf16 MFMA GEMM ------------------------------------------
// C[m][n] = scale * sum_k A[m][k]*B[n][k] (+ bias[n])
// A row-major [M][K] (lda), B stored [N][K] (ldb). 128x128 tile, BK=32,
// 4 waves of 64x64, mfma_f32_16x16x32_bf16, global_load_lds staging.
template <bool OUT_BF16, bool HAS_BIAS>
__global__ __launch_bounds__(256) void gemm_kernel(
    const unsigned short* __restrict__ A, int lda, size_t strideA,
    const unsigned short* __restrict__ B, int ldb, size_t strideB,
    void* __restrict__ Cv, int ldc, size_t strideC,
    const float* __restrict__ bias, float scale, int K)
{
    // linear, unpadded (required by global_load_lds): [128][32] bf16 = 8 KB each
    __shared__ unsigned short a_lds[128 * 32];
    __shared__ unsigned short b_lds[128 * 32];

    A += (size_t)blockIdx.z * strideA;
    B += (size_t)blockIdx.z * strideB;

    const int m0 = blockIdx.y * 128;
    const int n0 = blockIdx.x * 128;

    const int t    = threadIdx.x;
    const int lane = t & 63;
    const int w    = t >> 6;
    const int wm   = (w >> 1) * 64;
    const int wn   = (w & 1) * 64;
    const int fr   = lane & 15;   // A-row / B-col within fragment
    const int kg   = lane >> 4;   // k-group (8 elems each)

    // staging: wave w, instr i in {0,1}: chunk = w*128 + i*64 + lane (16B each)
    //   LDS dest (wave-uniform): elem offset w*1024 + i*512
    //   global row = w*32 + i*16 + (lane>>2), col = (lane&3)*8
    const int rA = w * 32 + (lane >> 2);
    const int cO = (lane & 3) * 8;
    const unsigned short* pA0 = A + (size_t)(m0 + rA) * lda + cO;
    const unsigned short* pA1 = A + (size_t)(m0 + rA + 16) * lda + cO;
    const unsigned short* pB0 = B + (size_t)(n0 + rA) * ldb + cO;
    const unsigned short* pB1 = B + (size_t)(n0 + rA + 16) * ldb + cO;
    unsigned short* ldsA0 = &a_lds[w * 1024];
    unsigned short* ldsA1 = &a_lds[w * 1024 + 512];
    unsigned short* ldsB0 = &b_lds[w * 1024];
    unsigned short* ldsB1 = &b_lds[w * 1024 + 512];

    f32x4 acc[4][4] = {};

    for (int k0 = 0; k0 < K; k0 += 32) {
        gload16(pA0 + k0, ldsA0);
        gload16(pA1 + k0, ldsA1);
        gload16(pB0 + k0, ldsB0);
        gload16(pB1 + k0, ldsB1);
        __syncthreads();   // compiler drains vmcnt(0) here (m97 behavior)

        bf16x8 af[4], bfr[4];
        #pragma unroll
        for (int m = 0; m < 4; ++m)
            af[m] = *reinterpret_cast<const bf16x8*>(&a_lds[(wm + m * 16 + fr) * 32 + kg * 8]);
        #pragma unroll
        for (int n = 0; n < 4; ++n)
            bfr[n] = *reinterpret_cast<const bf16x8*>(&b_lds[(wn + n * 16 + fr) * 32 + kg * 8]);

        #pragma unroll
        for (int m = 0; m < 4; ++m)
            #pragma unroll
            for (int n = 0; n < 4; ++n)
                acc[m][n] = __builtin_amdgcn_mfma_f32_16x16x32_bf16(
                    af[m], bfr[n], acc[m][n], 0, 0, 0);
        __syncthreads();
    }

    // epilogue: C/D layout col = lane&15, row = (lane>>4)*4 + r  [m89-verified]
    const int rbase = wm + (lane >> 4) * 4;
    const int cbase = wn + (lane & 15);
    const size_t zoff = (size_t)blockIdx.z * strideC;
    #pragma unroll
    for (int n = 0; n < 4; ++n) {
        const int col = n0 + cbase + n * 16;
        const float bsv = HAS_BIAS ? bias[col] : 0.0f;
        #pragma unroll
        for (int m = 0; m < 4; ++m) {
            #pragma unroll
            for (int r = 0; r < 4; ++r) {
                const int rowg = m0 + rbase + m * 16 + r;
                const float v = acc[m][n][r] * scale + bsv;
                if (OUT_BF16)
                    reinterpret_cast<unsigned short*>(Cv)[zoff + (size_t)rowg * ldc + col] = f2bf(v);
                else
                    reinterpret_cast<float*>(Cv)[zoff + (size_t)rowg * ldc + col] = v;
            }
        }
    }
}

// ---- stage 4: in-place row softmax on S (bf16), one block per row ----------
__global__ __launch_bounds__(256) void softmax_kernel(unsigned short* __restrict__ S) {
    __shared__ float red[8];
    unsigned short* p = S + (size_t)blockIdx.x * SEQ;
    const int t = threadIdx.x;  // 256 threads * 8 elems = 2048
    union { uint4 v; unsigned short u[8]; } in;
    in.v = reinterpret_cast<const uint4*>(p)[t];
    float f[8];
    float m = -1e30f;
    #pragma unroll
    for (int i = 0; i < 8; ++i) { f[i] = bf2f(in.u[i]); m = fmaxf(m, f[i]); }
    #pragma unroll
    for (int off = 32; off > 0; off >>= 1) m = fmaxf(m, __shfl_xor(m, off));
    if ((t & 63) == 0) red[t >> 6] = m;
    __syncthreads();
    m = fmaxf(fmaxf(red[0], red[1]), fmaxf(red[2], red[3]));
    float s = 0.0f;
    #pragma unroll
    for (int i = 0; i < 8; ++i) { f[i] = __expf(f[i] - m); s += f[i]; }
    #pragma unroll
    for (int off = 32; off > 0; off >>= 1) s += __shfl_xor(s, off);
    __syncthreads();
    if ((t & 63) == 0) red[4 + (t >> 6)] = s;
    __syncthreads();
    s = (red[4] + red[5]) + (red[6] + red[7]);
    const float inv = 1.0f / s;
    union { uint4 v; unsigned short u[8]; } o;
    #pragma unroll
    for (int i = 0; i < 8; ++i) o.u[i] = f2bf(f[i] * inv);
    reinterpret_cast<uint4*>(p)[t] = o.v;
}

// ---- stage 5a: V [s][h] (inside QKV, stride 3072) -> Vt [h][s] per batch ---
__global__ void transpose_v_kernel(const unsigned short* __restrict__ QKV,
                                   unsigned short* __restrict__ Vt) {
    __shared__ unsigned short tile[32][34];  // 17-dw row stride: conflict-free
    const int b = blockIdx.z;
    const int s0 = blockIdx.x * 32, h0 = blockIdx.y * 32;
    const int t = threadIdx.x, lr = t >> 5, lc = t & 31;
    const unsigned short* in = QKV + (size_t)b * SEQ * NQKV + 2 * DIM;
    #pragma unroll
    for (int r = 0; r < 4; ++r) {
        int si = r * 8 + lr;
        tile[si][lc] = in[(size_t)(s0 + si) * NQKV + h0 + lc];
    }
    __syncthreads();
    unsigned short* out = Vt + (size_t)b * DIM * SEQ;
    #pragma unroll
    for (int r = 0; r < 4; ++r) {
        int hi = r * 8 + lr;
        out[(size_t)(h0 + hi) * SEQ + s0 + lc] = tile[lc][hi];
    }
}

// ---------------------------------------------------------------------------
extern "C" void kernel_launch(void* const* d_in, const int* in_sizes, int n_in,
                              void* d_out, int out_size, void* d_ws, size_t ws_size,
                              hipStream_t stream) {
    const float* x  = (const float*)d_in[0];
    const float* Wq = (const float*)d_in[1];
    const float* bq = (const float*)d_in[2];
    const float* Wk = (const float*)d_in[3];
    const float* bk = (const float*)d_in[4];
    const float* Wv = (const float*)d_in[5];
    const float* bv = (const float*)d_in[6];
    float* out = (float*)d_out;
    char* ws = (char*)d_ws;

    // workspace layout (bytes); Vt aliases xb (xb dead after QKV GEMM)
    const size_t OFF_XB   = 0;                         // 8192*1024*2  = 16,777,216
    const size_t OFF_WT   = 16777216;                  // 3072*1024*2  =  6,291,456
    const size_t OFF_BIAS = 23068672;                  // 3072*4       =     12,288
    const size_t OFF_QKV  = 23080960;                  // 8192*3072*2  = 50,331,648
    const size_t OFF_S    = 73412608;                  // 4*2048*2048*2= 33,554,432
    // total ~102 MB (Vt reuses OFF_XB)

    unsigned short* xb   = (unsigned short*)(ws + OFF_XB);
    unsigned short* Wt   = (unsigned short*)(ws + OFF_WT);
    float*          bcat = (float*)(ws + OFF_BIAS);
    unsigned short* qkv  = (unsigned short*)(ws + OFF_QKV);
    unsigned short* Smat = (unsigned short*)(ws + OFF_S);
    unsigned short* Vt   = (unsigned short*)(ws + OFF_XB);  // alias

    // 1. casts / transposes
    cast_x_kernel<<<(MROWS * DIM / 8 + 255) / 256, 256, 0, stream>>>(x, xb, MROWS * DIM / 8);
    transpose_w_kernel<<<dim3(32, 32, 3), 256, 0, stream>>>(Wq, Wk, Wv, Wt);
    concat_bias_kernel<<<12, 256, 0, stream>>>(bq, bk, bv, bcat);

    // 2. QKV = x @ W^T + b : M=8192, N=3072, K=1024, bf16 out, ldc=3072
    gemm_kernel<true, true><<<dim3(NQKV / 128, MROWS / 128, 1), 256, 0, stream>>>(
        xb, DIM, 0, Wt, DIM, 0, qkv, NQKV, 0, bcat, 1.0f, DIM);

    // 3. S = Q @ K^T / 32 : per-batch, M=N=2048, K=1024, bf16 out
    gemm_kernel<true, false><<<dim3(SEQ / 128, SEQ / 128, BATCH), 256, 0, stream>>>(
        qkv, NQKV, (size_t)SEQ * NQKV,            // Q rows
        qkv + DIM, NQKV, (size_t)SEQ * NQKV,      // K rows ([N][K] layout already)
        Smat, SEQ, (size_t)SEQ * SEQ,
        nullptr, 1.0f / 32.0f, DIM);

    // 4. softmax rows in place
    softmax_kernel<<<BATCH * SEQ, 256, 0, stream>>>(Smat);

    // 5. V^T then O = P @ V : per-batch M=2048, N=1024, K=2048, fp32 out
    transpose_v_kernel<<<dim3(SEQ / 32, DIM / 32, BATCH), 256, 0, stream>>>(qkv, Vt);
    gemm_kernel<false, false><<<dim3(DIM / 128, SEQ / 128, BATCH), 256, 0, stream>>>(
        Smat, SEQ, (size_t)SEQ * SEQ,
        Vt, SEQ, (size_t)DIM * SEQ,
        out, DIM, (size_t)SEQ * DIM,
        nullptr, 1.0f, SEQ);
}